// Round 3
// baseline (367.715 us; speedup 1.0000x reference)
//
#include <hip/hip_runtime.h>
#include <hip/hip_bf16.h>

#define B_ 4
#define C_ 512
#define T_ 1024
#define SCALE_ 0.125f
#define EPS_ 1e-5f

typedef unsigned short u16;
typedef __attribute__((ext_vector_type(8))) unsigned short u16x8;
typedef __attribute__((ext_vector_type(4))) unsigned short u16x4;
typedef __attribute__((ext_vector_type(8))) short s16x8;
typedef __attribute__((ext_vector_type(4))) float f32x4;

// ws byte offsets
#define QT_OFF    (0x0ull)         // bf16 Qt[B][T][C]   4 MB
#define KT_OFF    (0x400000ull)    // bf16 Kt[B][T][C]   4 MB
#define V_OFF     (0x800000ull)    // bf16 V [B][C][T]   4 MB
#define XT_OFF    (0xC00000ull)    // bf16 Xt[B][T][C]   4 MB
#define OPART_OFF (0x1000000ull)   // fp32 Opart[B][2][64][16][512] 16 MB
#define LP_OFF    (0x2000000ull)   // fp32 lpart [B][2][8][1024] 256 KB
#define L2P_OFF   (0x2040000ull)   // fp32 l2part[B][2][8][1024] 256 KB
#define AB_OFF    (0x2080000ull)   // fp32 ab[B][8][2]
#define VSUM_OFF  (0x2090000ull)   // fp32 vsum[B][8][64]
#define O_OFF     (0x20A0000ull)   // bf16 O[B][8][T][64] 4 MB

static __device__ __forceinline__ u16 f2bf(float f) {
  unsigned u = __float_as_uint(f);
  unsigned r = (u + 0x7fff + ((u >> 16) & 1)) >> 16;  // RNE
  return (u16)r;
}
static __device__ __forceinline__ float b2f(u16 x) {
  return __uint_as_float(((unsigned)x) << 16);
}
static __device__ __forceinline__ f32x4 mfma16(s16x8 a, s16x8 b, f32x4 c) {
  return __builtin_amdgcn_mfma_f32_16x16x32_bf16(a, b, c, 0, 0, 0);
}

// ---------------- transpose x -> Xt[b][t][c] bf16 ----------------
__global__ __launch_bounds__(256) void transpose_x(const float* __restrict__ x,
                                                   u16* __restrict__ xt) {
  const int b = blockIdx.z;
  const int t0 = blockIdx.x << 6;
  const int c0 = blockIdx.y << 6;
  const float* __restrict__ X = x + (size_t)b * (C_ * (size_t)T_);
  u16* __restrict__ Xt = xt + (size_t)b * (T_ * (size_t)C_);
  __shared__ float Ts[64][65];
  const int tid = threadIdx.x;
#pragma unroll
  for (int i = 0; i < 4; ++i) {
    const int e = tid + (i << 8);
    const int r = e >> 4, c4 = e & 15;
    const float4 v = *(const float4*)(X + (size_t)(c0 + r) * T_ + t0 + (c4 << 2));
    Ts[r][(c4 << 2) + 0] = v.x; Ts[r][(c4 << 2) + 1] = v.y;
    Ts[r][(c4 << 2) + 2] = v.z; Ts[r][(c4 << 2) + 3] = v.w;
  }
  __syncthreads();
#pragma unroll
  for (int i = 0; i < 2; ++i) {
    const int e = tid + (i << 8);
    const int tt = e >> 3, c8 = e & 7;
    u16x8 o;
#pragma unroll
    for (int j = 0; j < 8; ++j) o[j] = f2bf(Ts[(c8 << 3) + j][tt]);
    *(u16x8*)(Xt + (size_t)(t0 + tt) * C_ + c0 + (c8 << 3)) = o;
  }
}

// ---------------- Qt/Kt = Xt @ W^T  -> [t][o] bf16 ----------------
__global__ __launch_bounds__(256) void gemm_qkt(const u16* __restrict__ xt,
                                                const float* __restrict__ wq,
                                                const float* __restrict__ wk,
                                                u16* __restrict__ qto,
                                                u16* __restrict__ kto) {
  const int which = blockIdx.z >> 2;
  const int b = blockIdx.z & 3;
  const float* __restrict__ W = which ? wk : wq;
  u16* __restrict__ Y = (which ? kto : qto) + (size_t)b * (T_ * (size_t)C_);
  const u16* __restrict__ A = xt + (size_t)b * (T_ * (size_t)C_);
  const int m0 = blockIdx.x << 7;  // t
  const int n0 = blockIdx.y << 7;  // o
  __shared__ u16 As[128][40];
  __shared__ u16 Bs[128][40];
  const int tid = threadIdx.x;
  const int w = tid >> 6, lane = tid & 63, lr = lane & 15, lq = lane >> 4;
  const int mw = (w >> 1) << 6, nw = (w & 1) << 6;
  f32x4 acc[4][4] = {};
  for (int k0 = 0; k0 < C_; k0 += 32) {
#pragma unroll
    for (int it = 0; it < 2; ++it) {
      const int e = tid + (it << 8);
      const int r = e >> 2, c4 = e & 3;
      *(u16x8*)&As[r][c4 << 3] =
          *(const u16x8*)(A + (size_t)(m0 + r) * C_ + k0 + (c4 << 3));
      const float* wr = W + (size_t)(n0 + r) * C_ + k0 + (c4 << 3);
      const float4 f0 = *(const float4*)wr;
      const float4 f1 = *(const float4*)(wr + 4);
      u16x8 o;
      o[0] = f2bf(f0.x); o[1] = f2bf(f0.y); o[2] = f2bf(f0.z); o[3] = f2bf(f0.w);
      o[4] = f2bf(f1.x); o[5] = f2bf(f1.y); o[6] = f2bf(f1.z); o[7] = f2bf(f1.w);
      *(u16x8*)&Bs[r][c4 << 3] = o;
    }
    __syncthreads();
    const int ko = lq << 3;
    s16x8 a[4], bb[4];
#pragma unroll
    for (int i = 0; i < 4; ++i) a[i] = *(const s16x8*)&As[mw + (i << 4) + lr][ko];
#pragma unroll
    for (int j = 0; j < 4; ++j) bb[j] = *(const s16x8*)&Bs[nw + (j << 4) + lr][ko];
#pragma unroll
    for (int i = 0; i < 4; ++i)
#pragma unroll
      for (int j = 0; j < 4; ++j) acc[i][j] = mfma16(a[i], bb[j], acc[i][j]);
    __syncthreads();
  }
#pragma unroll
  for (int i = 0; i < 4; ++i) {
    const int row = mw + (i << 4) + (lq << 2);
#pragma unroll
    for (int j = 0; j < 4; ++j) {
      const int col = nw + (j << 4) + lr;
#pragma unroll
      for (int r = 0; r < 4; ++r)
        Y[(size_t)(m0 + row + r) * C_ + n0 + col] = f2bf(acc[i][j][r]);
    }
  }
}

// ---------------- V = Wv @ X  -> [o][t] bf16 ----------------
__global__ __launch_bounds__(256) void gemm_v(const u16* __restrict__ xt,
                                              const float* __restrict__ wv,
                                              u16* __restrict__ vout) {
  const int b = blockIdx.z;
  const int n0 = blockIdx.x << 7;  // t
  const int m0 = blockIdx.y << 7;  // o
  const u16* __restrict__ Bg = xt + (size_t)b * (T_ * (size_t)C_);
  u16* __restrict__ Y = vout + (size_t)b * (C_ * (size_t)T_);
  __shared__ u16 As[128][40];
  __shared__ u16 Bs[128][40];
  const int tid = threadIdx.x;
  const int w = tid >> 6, lane = tid & 63, lr = lane & 15, lq = lane >> 4;
  const int mw = (w >> 1) << 6, nw = (w & 1) << 6;
  f32x4 acc[4][4] = {};
  for (int k0 = 0; k0 < C_; k0 += 32) {
#pragma unroll
    for (int it = 0; it < 2; ++it) {
      const int e = tid + (it << 8);
      const int r = e >> 2, c4 = e & 3;
      const float* wr = wv + (size_t)(m0 + r) * C_ + k0 + (c4 << 3);
      const float4 f0 = *(const float4*)wr;
      const float4 f1 = *(const float4*)(wr + 4);
      u16x8 o;
      o[0] = f2bf(f0.x); o[1] = f2bf(f0.y); o[2] = f2bf(f0.z); o[3] = f2bf(f0.w);
      o[4] = f2bf(f1.x); o[5] = f2bf(f1.y); o[6] = f2bf(f1.z); o[7] = f2bf(f1.w);
      *(u16x8*)&As[r][c4 << 3] = o;
      *(u16x8*)&Bs[r][c4 << 3] =
          *(const u16x8*)(Bg + (size_t)(n0 + r) * C_ + k0 + (c4 << 3));
    }
    __syncthreads();
    const int ko = lq << 3;
    s16x8 a[4], bb[4];
#pragma unroll
    for (int i = 0; i < 4; ++i) a[i] = *(const s16x8*)&As[mw + (i << 4) + lr][ko];
#pragma unroll
    for (int j = 0; j < 4; ++j) bb[j] = *(const s16x8*)&Bs[nw + (j << 4) + lr][ko];
#pragma unroll
    for (int i = 0; i < 4; ++i)
#pragma unroll
      for (int j = 0; j < 4; ++j) acc[i][j] = mfma16(a[i], bb[j], acc[i][j]);
    __syncthreads();
  }
#pragma unroll
  for (int i = 0; i < 4; ++i) {
    const int row = mw + (i << 4) + (lq << 2);
#pragma unroll
    for (int j = 0; j < 4; ++j) {
      const int col = nw + (j << 4) + lr;
#pragma unroll
      for (int r = 0; r < 4; ++r)
        Y[(size_t)(m0 + row + r) * T_ + n0 + col] = f2bf(acc[i][j][r]);
    }
  }
}

// ---------------- vsum[b][g][d] = sum_t V ----------------
__global__ __launch_bounds__(256) void vsum_k(const u16* __restrict__ v,
                                              float* __restrict__ vsum) {
  const int bg = blockIdx.x;  // b*8+g
  const int tid = threadIdx.x;
  const int d = tid >> 2, part = tid & 3;
  const u16* __restrict__ Vr =
      v + ((size_t)(bg >> 3) * C_ + ((bg & 7) << 6) + d) * T_ + (part << 8);
  float s = 0.f;
  for (int t = 0; t < 256; t += 8) {
    const u16x8 x = *(const u16x8*)(Vr + t);
#pragma unroll
    for (int j = 0; j < 8; ++j) s += b2f(x[j]);
  }
  s += __shfl_down(s, 2, 64);
  s += __shfl_down(s, 1, 64);
  if (part == 0) vsum[(bg << 6) + d] = s;
}

// ---------------- fused attention: QK^T -> mix -> exp -> PV ----------------
// block: (q16, half, b); 4 waves; wave w covers t = half*512 + iter*128 + w*32.
// S^T layout trick: C-frag of K*Q^T has q=lane&15, t=quad*4+reg -> directly a
// PV A-operand under a consistent k-slot permutation (j<4: t-sub 0, j>=4: sub 1).
// No max subtraction: mixed scores ~N(0,1); exp(s) is safe in fp32/bf16.
__global__ __launch_bounds__(256, 2) void fused_attn(
    const u16* __restrict__ Qt, const u16* __restrict__ Kt,
    const u16* __restrict__ V, const float* __restrict__ wh,
    float* __restrict__ Opart, float* __restrict__ lpart,
    float* __restrict__ l2part) {
  const int q16 = blockIdx.x;
  const int half = blockIdx.y;
  const int b = blockIdx.z;
  const int tid = threadIdx.x;
  const int w = tid >> 6, lane = tid & 63;
  const int lr = lane & 15, quad = lane >> 4;
  const int q0 = q16 << 4;

  const u16* __restrict__ Qb = Qt + ((size_t)b * T_ + q0) * C_;
  const u16* __restrict__ Kb = Kt + (size_t)b * T_ * C_;
  const u16* __restrict__ Vb = V + (size_t)b * C_ * T_;

  __shared__ u16 Qs[16][520];
  __shared__ float Ored[16][520];
  __shared__ float lred[2][4][8][16];

  for (int i = tid; i < 1024; i += 256) {
    const int r = i >> 6, c8 = i & 63;
    *(u16x8*)&Qs[r][c8 << 3] = *(const u16x8*)(Qb + (size_t)r * C_ + (c8 << 3));
  }

  float whv[64];
#pragma unroll
  for (int i = 0; i < 64; ++i) whv[i] = wh[i] * SCALE_;
  __syncthreads();

  f32x4 Oacc[8][4] = {};  // [g][dtile]
  float lsum[8] = {}, l2sum[8] = {};

  for (int iter = 0; iter < 4; ++iter) {
    const int tb = (half << 9) + (iter << 7) + (w << 5);
    f32x4 Sh[8][2];
#pragma unroll
    for (int h = 0; h < 8; ++h) {
      f32x4 a0 = {0.f, 0.f, 0.f, 0.f}, a1 = {0.f, 0.f, 0.f, 0.f};
#pragma unroll
      for (int kf = 0; kf < 2; ++kf) {
        const int co = (h << 6) + (kf << 5) + (quad << 3);
        const s16x8 qf = *(const s16x8*)&Qs[lr][co];
        const s16x8 k0 = *(const s16x8*)(Kb + (size_t)(tb + lr) * C_ + co);
        const s16x8 k1 = *(const s16x8*)(Kb + (size_t)(tb + 16 + lr) * C_ + co);
        a0 = mfma16(k0, qf, a0);
        a1 = mfma16(k1, qf, a1);
      }
      Sh[h][0] = a0;
      Sh[h][1] = a1;
    }
#pragma unroll
    for (int g = 0; g < 8; ++g) {
      f32x4 m0 = {0.f, 0.f, 0.f, 0.f}, m1 = {0.f, 0.f, 0.f, 0.f};
#pragma unroll
      for (int h = 0; h < 8; ++h) {
        const float wgh = whv[(g << 3) + h];
        m0 += Sh[h][0] * wgh;
        m1 += Sh[h][1] * wgh;
      }
      f32x4 e0, e1;
#pragma unroll
      for (int k = 0; k < 4; ++k) {
        e0[k] = __expf(m0[k]);
        e1[k] = __expf(m1[k]);
      }
      lsum[g] += e0[0] + e0[1] + e0[2] + e0[3] + e1[0] + e1[1] + e1[2] + e1[3];
      l2sum[g] += e0[0] * e0[0] + e0[1] * e0[1] + e0[2] * e0[2] + e0[3] * e0[3] +
                  e1[0] * e1[0] + e1[1] * e1[1] + e1[2] * e1[2] + e1[3] * e1[3];
      s16x8 pa;
#pragma unroll
      for (int k = 0; k < 4; ++k) {
        pa[k] = (short)f2bf(e0[k]);
        pa[k + 4] = (short)f2bf(e1[k]);
      }
#pragma unroll
      for (int dt = 0; dt < 4; ++dt) {
        const u16* vr =
            Vb + (size_t)((g << 6) + (dt << 4) + lr) * T_ + tb + (quad << 2);
        const u16x4 v0 = *(const u16x4*)vr;
        const u16x4 v1 = *(const u16x4*)(vr + 16);
        s16x8 vb;
#pragma unroll
        for (int k = 0; k < 4; ++k) {
          vb[k] = (short)v0[k];
          vb[k + 4] = (short)v1[k];
        }
        Oacc[g][dt] = mfma16(pa, vb, Oacc[g][dt]);
      }
    }
  }

  // reduce l across quads (each lane's q = lane&15)
#pragma unroll
  for (int g = 0; g < 8; ++g) {
    lsum[g] += __shfl_xor(lsum[g], 16, 64);
    lsum[g] += __shfl_xor(lsum[g], 32, 64);
    l2sum[g] += __shfl_xor(l2sum[g], 16, 64);
    l2sum[g] += __shfl_xor(l2sum[g], 32, 64);
  }
  // phased cross-wave O reduction in LDS
  for (int r = 0; r < 4; ++r) {
    if (w == r) {
#pragma unroll
      for (int g = 0; g < 8; ++g)
#pragma unroll
        for (int dt = 0; dt < 4; ++dt)
#pragma unroll
          for (int k = 0; k < 4; ++k) {
            const int q = (quad << 2) + k;
            const int c = (g << 6) + (dt << 4) + lr;
            if (r == 0)
              Ored[q][c] = Oacc[g][dt][k];
            else
              Ored[q][c] += Oacc[g][dt][k];
          }
    }
    __syncthreads();
  }
  if (lane < 16) {
#pragma unroll
    for (int g = 0; g < 8; ++g) {
      lred[0][w][g][lane] = lsum[g];
      lred[1][w][g][lane] = l2sum[g];
    }
  }
  __syncthreads();
  float* __restrict__ Op =
      Opart + ((size_t)((((b << 1) + half) << 6) + q16) << 13);
  for (int i = tid; i < 2048; i += 256) {
    const int q = i >> 7, c4 = (i & 127) << 2;
    *(float4*)(Op + (q << 9) + c4) = *(const float4*)&Ored[q][c4];
  }
  if (tid < 128) {
    const int g = tid >> 4, qq = tid & 15;
    lpart[((((b << 1) + half) << 3) + g) * 1024 + q0 + qq] =
        lred[0][0][g][qq] + lred[0][1][g][qq] + lred[0][2][g][qq] +
        lred[0][3][g][qq];
  } else {
    const int g = (tid - 128) >> 4, qq = tid & 15;
    l2part[((((b << 1) + half) << 3) + g) * 1024 + q0 + qq] =
        lred[1][0][g][qq] + lred[1][1][g][qq] + lred[1][2][g][qq] +
        lred[1][3][g][qq];
  }
}

// ---------------- stats: alpha/beta' per (b,g) ----------------
__global__ __launch_bounds__(256) void reduce_stats(
    const float* __restrict__ lpart, const float* __restrict__ l2part,
    const float* __restrict__ gamma, const float* __restrict__ beta,
    float* __restrict__ ab) {
  const int b = blockIdx.x >> 3, g = blockIdx.x & 7;
  const float* la = lpart + (((b << 1) << 3) + g) * 1024;
  const float* lb = lpart + ((((b << 1) + 1) << 3) + g) * 1024;
  const float* qa = l2part + (((b << 1) << 3) + g) * 1024;
  const float* qb = l2part + ((((b << 1) + 1) << 3) + g) * 1024;
  const int tid = threadIdx.x;
  float s = 0.f;
  for (int q = tid; q < 1024; q += 256) {
    const float l = la[q] + lb[q];
    const float l2v = qa[q] + qb[q];
    s += l2v / (l * l);
  }
#pragma unroll
  for (int off = 32; off; off >>= 1) s += __shfl_xor(s, off, 64);
  __shared__ float red[4];
  if ((tid & 63) == 0) red[tid >> 6] = s;
  __syncthreads();
  if (tid == 0) {
    const float ssq = red[0] + red[1] + red[2] + red[3];
    const float mean = 0.0009765625f;
    const float var = ssq * (1.f / 1048576.f) - mean * mean;
    const float al = gamma[g] * rsqrtf(var + EPS_);
    ab[blockIdx.x * 2] = al;
    ab[blockIdx.x * 2 + 1] = beta[g] - al * mean;
  }
}

// ---------------- combine halves + normalize + affine -> O bf16 ----------------
__global__ __launch_bounds__(256) void combine(const float* __restrict__ Opart,
                                               const float* __restrict__ lpart,
                                               const float* __restrict__ ab,
                                               const float* __restrict__ vsum,
                                               u16* __restrict__ O) {
  const int blk = blockIdx.x, b = blk >> 6, q16 = blk & 63;
  const float* Oa = Opart + ((size_t)(((b << 1) << 6) + q16) << 13);
  const float* Ob = Opart + ((size_t)((((b << 1) + 1) << 6) + q16) << 13);
  const int tid = threadIdx.x;
  for (int i = tid; i < 2048; i += 256) {
    const int q = i >> 7, c4 = (i & 127) << 2;
    const int g = c4 >> 6, d = c4 & 63;
    const float4 a = *(const float4*)(Oa + (q << 9) + c4);
    const float4 bb = *(const float4*)(Ob + (q << 9) + c4);
    const int qglob = (q16 << 4) + q;
    const float lt = lpart[(((b << 1) << 3) + g) * 1024 + qglob] +
                     lpart[((((b << 1) + 1) << 3) + g) * 1024 + qglob];
    const float al = ab[(((b << 3) + g) << 1)];
    const float bp2 = ab[(((b << 3) + g) << 1) + 1];
    const float inv = al / lt;
    const float* vs = vsum + (((b << 3) + g) << 6) + d;
    u16x4 o;
    o[0] = f2bf((a.x + bb.x) * inv + bp2 * vs[0]);
    o[1] = f2bf((a.y + bb.y) * inv + bp2 * vs[1]);
    o[2] = f2bf((a.z + bb.z) * inv + bp2 * vs[2]);
    o[3] = f2bf((a.w + bb.w) * inv + bp2 * vs[3]);
    *(u16x4*)(O + ((size_t)(((b << 3) + g) * T_ + qglob) << 6) + d) = o;
  }
}

// ---------------- y = M @ Wp^T + bp,  M gathered from O ----------------
__global__ __launch_bounds__(256) void gemm_proj(const u16* __restrict__ O,
                                                 const float* __restrict__ wp,
                                                 const float* __restrict__ bp,
                                                 float* __restrict__ y) {
  const int b = blockIdx.z;
  const int m0 = blockIdx.y << 7;  // o
  const int n0 = blockIdx.x << 7;  // t
  const u16* __restrict__ Ob = O + (size_t)b * (8 * T_ * 64);
  __shared__ u16 As[128][40];
  __shared__ u16 Bs[128][40];
  const int tid = threadIdx.x;
  const int w = tid >> 6, lane = tid & 63, lr = lane & 15, lq = lane >> 4;
  const int mw = (w >> 1) << 6, nw = (w & 1) << 6;
  f32x4 acc[4][4] = {};
  for (int k0 = 0; k0 < C_; k0 += 32) {
#pragma unroll
    for (int it = 0; it < 2; ++it) {
      const int e = tid + (it << 8);
      const int r = e >> 2, c4 = e & 3;
      const float* wr = wp + (size_t)(m0 + r) * C_ + k0 + (c4 << 3);
      const float4 f0 = *(const float4*)wr;
      const float4 f1 = *(const float4*)(wr + 4);
      u16x8 o;
      o[0] = f2bf(f0.x); o[1] = f2bf(f0.y); o[2] = f2bf(f0.z); o[3] = f2bf(f0.w);
      o[4] = f2bf(f1.x); o[5] = f2bf(f1.y); o[6] = f2bf(f1.z); o[7] = f2bf(f1.w);
      *(u16x8*)&As[r][c4 << 3] = o;
      const int t = n0 + r;
      const int c = k0 + (c4 << 3);
      *(u16x8*)&Bs[r][c4 << 3] =
          *(const u16x8*)(Ob + (size_t)(t >> 7) * (T_ * 64) +
                          (size_t)(((t & 127) << 3) + (c >> 6)) * 64 + (c & 63));
    }
    __syncthreads();
    const int ko = lq << 3;
    s16x8 a[4], bb[4];
#pragma unroll
    for (int i = 0; i < 4; ++i) a[i] = *(const s16x8*)&As[mw + (i << 4) + lr][ko];
#pragma unroll
    for (int j = 0; j < 4; ++j) bb[j] = *(const s16x8*)&Bs[nw + (j << 4) + lr][ko];
#pragma unroll
    for (int i = 0; i < 4; ++i)
#pragma unroll
      for (int j = 0; j < 4; ++j) acc[i][j] = mfma16(a[i], bb[j], acc[i][j]);
    __syncthreads();
  }
#pragma unroll
  for (int i = 0; i < 4; ++i) {
    const int row = mw + (i << 4) + (lq << 2);
#pragma unroll
    for (int j = 0; j < 4; ++j) {
      const int col = nw + (j << 4) + lr;
#pragma unroll
      for (int r = 0; r < 4; ++r)
        y[(size_t)b * (C_ * (size_t)T_) + (size_t)(m0 + row + r) * T_ + n0 + col] =
            acc[i][j][r] + bp[m0 + row + r];
    }
  }
}

extern "C" void kernel_launch(void* const* d_in, const int* in_sizes, int n_in,
                              void* d_out, int out_size, void* d_ws,
                              size_t ws_size, hipStream_t stream) {
  const float* x = (const float*)d_in[0];
  const float* wq = (const float*)d_in[1];
  const float* wk = (const float*)d_in[2];
  const float* wv = (const float*)d_in[3];
  const float* wh = (const float*)d_in[4];
  const float* gm = (const float*)d_in[5];
  const float* bt = (const float*)d_in[6];
  const float* wp = (const float*)d_in[7];
  const float* bp = (const float*)d_in[8];
  float* y = (float*)d_out;
  char* wsb = (char*)d_ws;

  u16* Qt = (u16*)(wsb + QT_OFF);
  u16* Kt = (u16*)(wsb + KT_OFF);
  u16* V = (u16*)(wsb + V_OFF);
  u16* Xt = (u16*)(wsb + XT_OFF);
  float* Opart = (float*)(wsb + OPART_OFF);
  float* lpart = (float*)(wsb + LP_OFF);
  float* l2part = (float*)(wsb + L2P_OFF);
  float* ab = (float*)(wsb + AB_OFF);
  float* vsum = (float*)(wsb + VSUM_OFF);
  u16* Og = (u16*)(wsb + O_OFF);

  transpose_x<<<dim3(16, 8, 4), 256, 0, stream>>>(x, Xt);
  gemm_qkt<<<dim3(8, 4, 8), 256, 0, stream>>>(Xt, wq, wk, Qt, Kt);
  gemm_v<<<dim3(8, 4, 4), 256, 0, stream>>>(Xt, wv, V);
  vsum_k<<<dim3(32), 256, 0, stream>>>(V, vsum);
  fused_attn<<<dim3(64, 2, 4), 256, 0, stream>>>(Qt, Kt, V, wh, Opart, lpart,
                                                 l2part);
  reduce_stats<<<dim3(32), 256, 0, stream>>>(lpart, l2part, gm, bt, ab);
  combine<<<dim3(256), 256, 0, stream>>>(Opart, lpart, ab, vsum, Og);
  gemm_proj<<<dim3(8, 4, 4), 256, 0, stream>>>(Og, wp, bp, y);
}

// Round 4
// 289.900 us; speedup vs baseline: 1.2684x; 1.2684x over previous
//
#include <hip/hip_runtime.h>
#include <hip/hip_bf16.h>

#define B_ 4
#define C_ 512
#define T_ 1024
#define SCALE_ 0.125f
#define EPS_ 1e-5f

typedef unsigned short u16;
typedef __attribute__((ext_vector_type(8))) unsigned short u16x8;
typedef __attribute__((ext_vector_type(4))) unsigned short u16x4;
typedef __attribute__((ext_vector_type(8))) short s16x8;
typedef __attribute__((ext_vector_type(4))) float f32x4;

// ws byte offsets
#define QT_OFF    (0x0ull)         // bf16 Qt[B][T][C]   4 MB  (Q pre-scaled by 1/8)
#define KT_OFF    (0x400000ull)    // bf16 Kt[B][T][C]   4 MB
#define V_OFF     (0x800000ull)    // bf16 V [B][C][T]   4 MB
#define XT_OFF    (0xC00000ull)    // bf16 Xt[B][T][C]   4 MB
#define OPART_OFF (0x1000000ull)   // bf16 Opart[B][2][64][16][512] 8 MB
#define LP_OFF    (0x2000000ull)   // fp32 lpart [B][2][8][1024] 256 KB
#define L2P_OFF   (0x2040000ull)   // fp32 l2part[B][2][8][1024] 256 KB
#define AB_OFF    (0x2080000ull)   // fp32 ab[B][8][2]
#define VSUM_OFF  (0x2090000ull)   // fp32 vsum[B][8][64]
#define O_OFF     (0x20A0000ull)   // bf16 O[B][8][T][64] 4 MB

static __device__ __forceinline__ u16 f2bf(float f) {
  unsigned u = __float_as_uint(f);
  unsigned r = (u + 0x7fff + ((u >> 16) & 1)) >> 16;  // RNE
  return (u16)r;
}
static __device__ __forceinline__ float b2f(u16 x) {
  return __uint_as_float(((unsigned)x) << 16);
}
static __device__ __forceinline__ f32x4 mfma16(s16x8 a, s16x8 b, f32x4 c) {
  return __builtin_amdgcn_mfma_f32_16x16x32_bf16(a, b, c, 0, 0, 0);
}

// ---------------- transpose x -> Xt[b][t][c] bf16 ----------------
__global__ __launch_bounds__(256) void transpose_x(const float* __restrict__ x,
                                                   u16* __restrict__ xt) {
  const int b = blockIdx.z;
  const int t0 = blockIdx.x << 6;
  const int c0 = blockIdx.y << 6;
  const float* __restrict__ X = x + (size_t)b * (C_ * (size_t)T_);
  u16* __restrict__ Xt = xt + (size_t)b * (T_ * (size_t)C_);
  __shared__ float Ts[64][65];
  const int tid = threadIdx.x;
#pragma unroll
  for (int i = 0; i < 4; ++i) {
    const int e = tid + (i << 8);
    const int r = e >> 4, c4 = e & 15;
    const float4 v = *(const float4*)(X + (size_t)(c0 + r) * T_ + t0 + (c4 << 2));
    Ts[r][(c4 << 2) + 0] = v.x; Ts[r][(c4 << 2) + 1] = v.y;
    Ts[r][(c4 << 2) + 2] = v.z; Ts[r][(c4 << 2) + 3] = v.w;
  }
  __syncthreads();
#pragma unroll
  for (int i = 0; i < 2; ++i) {
    const int e = tid + (i << 8);
    const int tt = e >> 3, c8 = e & 7;
    u16x8 o;
#pragma unroll
    for (int j = 0; j < 8; ++j) o[j] = f2bf(Ts[(c8 << 3) + j][tt]);
    *(u16x8*)(Xt + (size_t)(t0 + tt) * C_ + c0 + (c8 << 3)) = o;
  }
}

// ---------------- Qt/Kt = Xt @ W^T  -> [t][o] bf16 (Q scaled by 1/8) --------
__global__ __launch_bounds__(256) void gemm_qkt(const u16* __restrict__ xt,
                                                const float* __restrict__ wq,
                                                const float* __restrict__ wk,
                                                u16* __restrict__ qto,
                                                u16* __restrict__ kto) {
  const int which = blockIdx.z >> 2;
  const int b = blockIdx.z & 3;
  const float* __restrict__ W = which ? wk : wq;
  u16* __restrict__ Y = (which ? kto : qto) + (size_t)b * (T_ * (size_t)C_);
  const u16* __restrict__ A = xt + (size_t)b * (T_ * (size_t)C_);
  const float sc = which ? 1.0f : SCALE_;
  const int m0 = blockIdx.x << 7;  // t
  const int n0 = blockIdx.y << 7;  // o
  __shared__ u16 As[128][40];
  __shared__ u16 Bs[128][40];
  const int tid = threadIdx.x;
  const int w = tid >> 6, lane = tid & 63, lr = lane & 15, lq = lane >> 4;
  const int mw = (w >> 1) << 6, nw = (w & 1) << 6;
  f32x4 acc[4][4] = {};
  for (int k0 = 0; k0 < C_; k0 += 32) {
#pragma unroll
    for (int it = 0; it < 2; ++it) {
      const int e = tid + (it << 8);
      const int r = e >> 2, c4 = e & 3;
      *(u16x8*)&As[r][c4 << 3] =
          *(const u16x8*)(A + (size_t)(m0 + r) * C_ + k0 + (c4 << 3));
      const float* wr = W + (size_t)(n0 + r) * C_ + k0 + (c4 << 3);
      const float4 f0 = *(const float4*)wr;
      const float4 f1 = *(const float4*)(wr + 4);
      u16x8 o;
      o[0] = f2bf(f0.x); o[1] = f2bf(f0.y); o[2] = f2bf(f0.z); o[3] = f2bf(f0.w);
      o[4] = f2bf(f1.x); o[5] = f2bf(f1.y); o[6] = f2bf(f1.z); o[7] = f2bf(f1.w);
      *(u16x8*)&Bs[r][c4 << 3] = o;
    }
    __syncthreads();
    const int ko = lq << 3;
    s16x8 a[4], bb[4];
#pragma unroll
    for (int i = 0; i < 4; ++i) a[i] = *(const s16x8*)&As[mw + (i << 4) + lr][ko];
#pragma unroll
    for (int j = 0; j < 4; ++j) bb[j] = *(const s16x8*)&Bs[nw + (j << 4) + lr][ko];
#pragma unroll
    for (int i = 0; i < 4; ++i)
#pragma unroll
      for (int j = 0; j < 4; ++j) acc[i][j] = mfma16(a[i], bb[j], acc[i][j]);
    __syncthreads();
  }
#pragma unroll
  for (int i = 0; i < 4; ++i) {
    const int row = mw + (i << 4) + (lq << 2);
#pragma unroll
    for (int j = 0; j < 4; ++j) {
      const int col = nw + (j << 4) + lr;
#pragma unroll
      for (int r = 0; r < 4; ++r)
        Y[(size_t)(m0 + row + r) * C_ + n0 + col] = f2bf(acc[i][j][r] * sc);
    }
  }
}

// ---------------- V = Wv @ X  -> [o][t] bf16 ----------------
__global__ __launch_bounds__(256) void gemm_v(const u16* __restrict__ xt,
                                              const float* __restrict__ wv,
                                              u16* __restrict__ vout) {
  const int b = blockIdx.z;
  const int n0 = blockIdx.x << 7;  // t
  const int m0 = blockIdx.y << 7;  // o
  const u16* __restrict__ Bg = xt + (size_t)b * (T_ * (size_t)C_);
  u16* __restrict__ Y = vout + (size_t)b * (C_ * (size_t)T_);
  __shared__ u16 As[128][40];
  __shared__ u16 Bs[128][40];
  const int tid = threadIdx.x;
  const int w = tid >> 6, lane = tid & 63, lr = lane & 15, lq = lane >> 4;
  const int mw = (w >> 1) << 6, nw = (w & 1) << 6;
  f32x4 acc[4][4] = {};
  for (int k0 = 0; k0 < C_; k0 += 32) {
#pragma unroll
    for (int it = 0; it < 2; ++it) {
      const int e = tid + (it << 8);
      const int r = e >> 2, c4 = e & 3;
      const float* wr = wv + (size_t)(m0 + r) * C_ + k0 + (c4 << 3);
      const float4 f0 = *(const float4*)wr;
      const float4 f1 = *(const float4*)(wr + 4);
      u16x8 o;
      o[0] = f2bf(f0.x); o[1] = f2bf(f0.y); o[2] = f2bf(f0.z); o[3] = f2bf(f0.w);
      o[4] = f2bf(f1.x); o[5] = f2bf(f1.y); o[6] = f2bf(f1.z); o[7] = f2bf(f1.w);
      *(u16x8*)&As[r][c4 << 3] = o;
      *(u16x8*)&Bs[r][c4 << 3] =
          *(const u16x8*)(Bg + (size_t)(n0 + r) * C_ + k0 + (c4 << 3));
    }
    __syncthreads();
    const int ko = lq << 3;
    s16x8 a[4], bb[4];
#pragma unroll
    for (int i = 0; i < 4; ++i) a[i] = *(const s16x8*)&As[mw + (i << 4) + lr][ko];
#pragma unroll
    for (int j = 0; j < 4; ++j) bb[j] = *(const s16x8*)&Bs[nw + (j << 4) + lr][ko];
#pragma unroll
    for (int i = 0; i < 4; ++i)
#pragma unroll
      for (int j = 0; j < 4; ++j) acc[i][j] = mfma16(a[i], bb[j], acc[i][j]);
    __syncthreads();
  }
#pragma unroll
  for (int i = 0; i < 4; ++i) {
    const int row = mw + (i << 4) + (lq << 2);
#pragma unroll
    for (int j = 0; j < 4; ++j) {
      const int col = nw + (j << 4) + lr;
#pragma unroll
      for (int r = 0; r < 4; ++r)
        Y[(size_t)(m0 + row + r) * T_ + n0 + col] = f2bf(acc[i][j][r]);
    }
  }
}

// ---------------- vsum[b][g][d] = sum_t V ----------------
__global__ __launch_bounds__(256) void vsum_k(const u16* __restrict__ v,
                                              float* __restrict__ vsum) {
  const int bg = blockIdx.x;  // b*8+g
  const int tid = threadIdx.x;
  const int d = tid >> 2, part = tid & 3;
  const u16* __restrict__ Vr =
      v + ((size_t)(bg >> 3) * C_ + ((bg & 7) << 6) + d) * T_ + (part << 8);
  float s = 0.f;
  for (int t = 0; t < 256; t += 8) {
    const u16x8 x = *(const u16x8*)(Vr + t);
#pragma unroll
    for (int j = 0; j < 8; ++j) s += b2f(x[j]);
  }
  s += __shfl_down(s, 2, 64);
  s += __shfl_down(s, 1, 64);
  if (part == 0) vsum[(bg << 6) + d] = s;
}

// ---------------- fused attention: QK^T -> mix -> exp -> PV ----------------
// Register economy: no per-lane wh array (uniform s_load), h-outer mix into
// m[8][2], iter loop NOT unrolled. Oacc[8][4] maps to AGPRs.
__global__ __launch_bounds__(256, 2) void fused_attn(
    const u16* __restrict__ Qt, const u16* __restrict__ Kt,
    const u16* __restrict__ V, const float* __restrict__ wh,
    u16* __restrict__ Opart, float* __restrict__ lpart,
    float* __restrict__ l2part) {
  const int q16 = blockIdx.x;
  const int half = blockIdx.y;
  const int b = blockIdx.z;
  const int tid = threadIdx.x;
  const int w = tid >> 6, lane = tid & 63;
  const int lr = lane & 15, quad = lane >> 4;
  const int q0 = q16 << 4;

  const u16* __restrict__ Qb = Qt + ((size_t)b * T_ + q0) * C_;
  const u16* __restrict__ Kb = Kt + (size_t)b * T_ * C_;
  const u16* __restrict__ Vb = V + (size_t)b * C_ * T_;

  __shared__ u16 Qs[16][520];
  __shared__ float Ored[16][520];
  __shared__ float lred[2][4][8][16];

  for (int i = tid; i < 1024; i += 256) {
    const int r = i >> 6, c8 = i & 63;
    *(u16x8*)&Qs[r][c8 << 3] = *(const u16x8*)(Qb + (size_t)r * C_ + (c8 << 3));
  }
  __syncthreads();

  f32x4 Oacc[8][4] = {};  // [g][dtile] -> AGPRs
  float lsum[8] = {}, l2sum[8] = {};

#pragma unroll 1
  for (int iter = 0; iter < 4; ++iter) {
    const int tb = (half << 9) + (iter << 7) + (w << 5);
    // phase A: QK + head-mix, h-outer
    f32x4 m[8][2] = {};
#pragma unroll
    for (int h = 0; h < 8; ++h) {
      f32x4 a0 = {0.f, 0.f, 0.f, 0.f}, a1 = {0.f, 0.f, 0.f, 0.f};
#pragma unroll
      for (int kf = 0; kf < 2; ++kf) {
        const int co = (h << 6) + (kf << 5) + (quad << 3);
        const s16x8 qf = *(const s16x8*)&Qs[lr][co];
        const s16x8 k0 = *(const s16x8*)(Kb + (size_t)(tb + lr) * C_ + co);
        const s16x8 k1 = *(const s16x8*)(Kb + (size_t)(tb + 16 + lr) * C_ + co);
        a0 = mfma16(k0, qf, a0);
        a1 = mfma16(k1, qf, a1);
      }
#pragma unroll
      for (int g = 0; g < 8; ++g) {
        const float wgh = wh[(g << 3) + h];  // uniform -> SGPR
        m[g][0] += a0 * wgh;
        m[g][1] += a1 * wgh;
      }
    }
    // phase B: exp + PV
#pragma unroll
    for (int g = 0; g < 8; ++g) {
      f32x4 e0, e1;
#pragma unroll
      for (int k = 0; k < 4; ++k) {
        e0[k] = __expf(m[g][0][k]);
        e1[k] = __expf(m[g][1][k]);
      }
      lsum[g] += e0[0] + e0[1] + e0[2] + e0[3] + e1[0] + e1[1] + e1[2] + e1[3];
      l2sum[g] += e0[0] * e0[0] + e0[1] * e0[1] + e0[2] * e0[2] + e0[3] * e0[3] +
                  e1[0] * e1[0] + e1[1] * e1[1] + e1[2] * e1[2] + e1[3] * e1[3];
      s16x8 pa;
#pragma unroll
      for (int k = 0; k < 4; ++k) {
        pa[k] = (short)f2bf(e0[k]);
        pa[k + 4] = (short)f2bf(e1[k]);
      }
#pragma unroll
      for (int dt = 0; dt < 4; ++dt) {
        const u16* vr =
            Vb + (size_t)((g << 6) + (dt << 4) + lr) * T_ + tb + (quad << 2);
        const u16x4 v0 = *(const u16x4*)vr;
        const u16x4 v1 = *(const u16x4*)(vr + 16);
        s16x8 vb;
#pragma unroll
        for (int k = 0; k < 4; ++k) {
          vb[k] = (short)v0[k];
          vb[k + 4] = (short)v1[k];
        }
        Oacc[g][dt] = mfma16(pa, vb, Oacc[g][dt]);
      }
    }
  }

  // reduce l across quads (each lane's q = lane&15)
#pragma unroll
  for (int g = 0; g < 8; ++g) {
    lsum[g] += __shfl_xor(lsum[g], 16, 64);
    lsum[g] += __shfl_xor(lsum[g], 32, 64);
    l2sum[g] += __shfl_xor(l2sum[g], 16, 64);
    l2sum[g] += __shfl_xor(l2sum[g], 32, 64);
  }
  // phased cross-wave O reduction in LDS
#pragma unroll 1
  for (int r = 0; r < 4; ++r) {
    if (w == r) {
#pragma unroll
      for (int g = 0; g < 8; ++g)
#pragma unroll
        for (int dt = 0; dt < 4; ++dt)
#pragma unroll
          for (int k = 0; k < 4; ++k) {
            const int q = (quad << 2) + k;
            const int c = (g << 6) + (dt << 4) + lr;
            if (r == 0)
              Ored[q][c] = Oacc[g][dt][k];
            else
              Ored[q][c] += Oacc[g][dt][k];
          }
    }
    __syncthreads();
  }
  if (lane < 16) {
#pragma unroll
    for (int g = 0; g < 8; ++g) {
      lred[0][w][g][lane] = lsum[g];
      lred[1][w][g][lane] = l2sum[g];
    }
  }
  __syncthreads();
  u16* __restrict__ Op =
      Opart + ((size_t)((((b << 1) + half) << 6) + q16) << 13);
  for (int i = tid; i < 2048; i += 256) {
    const int q = i >> 7, c4 = (i & 127) << 2;
    const float4 v = *(const float4*)&Ored[q][c4];
    u16x4 o;
    o[0] = f2bf(v.x); o[1] = f2bf(v.y); o[2] = f2bf(v.z); o[3] = f2bf(v.w);
    *(u16x4*)(Op + (q << 9) + c4) = o;
  }
  if (tid < 128) {
    const int g = tid >> 4, qq = tid & 15;
    lpart[((((b << 1) + half) << 3) + g) * 1024 + q0 + qq] =
        lred[0][0][g][qq] + lred[0][1][g][qq] + lred[0][2][g][qq] +
        lred[0][3][g][qq];
  } else {
    const int g = (tid - 128) >> 4, qq = tid & 15;
    l2part[((((b << 1) + half) << 3) + g) * 1024 + q0 + qq] =
        lred[1][0][g][qq] + lred[1][1][g][qq] + lred[1][2][g][qq] +
        lred[1][3][g][qq];
  }
}

// ---------------- stats: alpha/beta' per (b,g) ----------------
__global__ __launch_bounds__(256) void reduce_stats(
    const float* __restrict__ lpart, const float* __restrict__ l2part,
    const float* __restrict__ gamma, const float* __restrict__ beta,
    float* __restrict__ ab) {
  const int b = blockIdx.x >> 3, g = blockIdx.x & 7;
  const float* la = lpart + (((b << 1) << 3) + g) * 1024;
  const float* lb = lpart + ((((b << 1) + 1) << 3) + g) * 1024;
  const float* qa = l2part + (((b << 1) << 3) + g) * 1024;
  const float* qb = l2part + ((((b << 1) + 1) << 3) + g) * 1024;
  const int tid = threadIdx.x;
  float s = 0.f;
  for (int q = tid; q < 1024; q += 256) {
    const float l = la[q] + lb[q];
    const float l2v = qa[q] + qb[q];
    s += l2v / (l * l);
  }
#pragma unroll
  for (int off = 32; off; off >>= 1) s += __shfl_xor(s, off, 64);
  __shared__ float red[4];
  if ((tid & 63) == 0) red[tid >> 6] = s;
  __syncthreads();
  if (tid == 0) {
    const float ssq = red[0] + red[1] + red[2] + red[3];
    const float mean = 0.0009765625f;
    const float var = ssq * (1.f / 1048576.f) - mean * mean;
    const float al = gamma[g] * rsqrtf(var + EPS_);
    ab[blockIdx.x * 2] = al;
    ab[blockIdx.x * 2 + 1] = beta[g] - al * mean;
  }
}

// ---------------- combine halves + normalize + affine -> O bf16 ----------------
__global__ __launch_bounds__(256) void combine(const u16* __restrict__ Opart,
                                               const float* __restrict__ lpart,
                                               const float* __restrict__ ab,
                                               const float* __restrict__ vsum,
                                               u16* __restrict__ O) {
  const int blk = blockIdx.x, b = blk >> 6, q16 = blk & 63;
  const u16* Oa = Opart + ((size_t)(((b << 1) << 6) + q16) << 13);
  const u16* Ob = Opart + ((size_t)((((b << 1) + 1) << 6) + q16) << 13);
  const int tid = threadIdx.x;
  for (int i = tid; i < 2048; i += 256) {
    const int q = i >> 7, c4 = (i & 127) << 2;
    const int g = c4 >> 6, d = c4 & 63;
    const u16x4 a = *(const u16x4*)(Oa + (q << 9) + c4);
    const u16x4 bb = *(const u16x4*)(Ob + (q << 9) + c4);
    const int qglob = (q16 << 4) + q;
    const float lt = lpart[(((b << 1) << 3) + g) * 1024 + qglob] +
                     lpart[((((b << 1) + 1) << 3) + g) * 1024 + qglob];
    const float al = ab[(((b << 3) + g) << 1)];
    const float bp2 = ab[(((b << 3) + g) << 1) + 1];
    const float inv = al / lt;
    const float* vs = vsum + (((b << 3) + g) << 6) + d;
    u16x4 o;
    o[0] = f2bf((b2f(a[0]) + b2f(bb[0])) * inv + bp2 * vs[0]);
    o[1] = f2bf((b2f(a[1]) + b2f(bb[1])) * inv + bp2 * vs[1]);
    o[2] = f2bf((b2f(a[2]) + b2f(bb[2])) * inv + bp2 * vs[2]);
    o[3] = f2bf((b2f(a[3]) + b2f(bb[3])) * inv + bp2 * vs[3]);
    *(u16x4*)(O + ((size_t)(((b << 3) + g) * T_ + qglob) << 6) + d) = o;
  }
}

// ---------------- y = M @ Wp^T + bp,  M gathered from O ----------------
__global__ __launch_bounds__(256) void gemm_proj(const u16* __restrict__ O,
                                                 const float* __restrict__ wp,
                                                 const float* __restrict__ bp,
                                                 float* __restrict__ y) {
  const int b = blockIdx.z;
  const int m0 = blockIdx.y << 7;  // o
  const int n0 = blockIdx.x << 7;  // t
  const u16* __restrict__ Ob = O + (size_t)b * (8 * T_ * 64);
  __shared__ u16 As[128][40];
  __shared__ u16 Bs[128][40];
  const int tid = threadIdx.x;
  const int w = tid >> 6, lane = tid & 63, lr = lane & 15, lq = lane >> 4;
  const int mw = (w >> 1) << 6, nw = (w & 1) << 6;
  f32x4 acc[4][4] = {};
  for (int k0 = 0; k0 < C_; k0 += 32) {
#pragma unroll
    for (int it = 0; it < 2; ++it) {
      const int e = tid + (it << 8);
      const int r = e >> 2, c4 = e & 3;
      const float* wr = wp + (size_t)(m0 + r) * C_ + k0 + (c4 << 3);
      const float4 f0 = *(const float4*)wr;
      const float4 f1 = *(const float4*)(wr + 4);
      u16x8 o;
      o[0] = f2bf(f0.x); o[1] = f2bf(f0.y); o[2] = f2bf(f0.z); o[3] = f2bf(f0.w);
      o[4] = f2bf(f1.x); o[5] = f2bf(f1.y); o[6] = f2bf(f1.z); o[7] = f2bf(f1.w);
      *(u16x8*)&As[r][c4 << 3] = o;
      const int t = n0 + r;
      const int c = k0 + (c4 << 3);
      *(u16x8*)&Bs[r][c4 << 3] =
          *(const u16x8*)(Ob + (size_t)(t >> 7) * (T_ * 64) +
                          (size_t)(((t & 127) << 3) + (c >> 6)) * 64 + (c & 63));
    }
    __syncthreads();
    const int ko = lq << 3;
    s16x8 a[4], bb[4];
#pragma unroll
    for (int i = 0; i < 4; ++i) a[i] = *(const s16x8*)&As[mw + (i << 4) + lr][ko];
#pragma unroll
    for (int j = 0; j < 4; ++j) bb[j] = *(const s16x8*)&Bs[nw + (j << 4) + lr][ko];
#pragma unroll
    for (int i = 0; i < 4; ++i)
#pragma unroll
      for (int j = 0; j < 4; ++j) acc[i][j] = mfma16(a[i], bb[j], acc[i][j]);
    __syncthreads();
  }
#pragma unroll
  for (int i = 0; i < 4; ++i) {
    const int row = mw + (i << 4) + (lq << 2);
#pragma unroll
    for (int j = 0; j < 4; ++j) {
      const int col = nw + (j << 4) + lr;
#pragma unroll
      for (int r = 0; r < 4; ++r)
        y[(size_t)b * (C_ * (size_t)T_) + (size_t)(m0 + row + r) * T_ + n0 + col] =
            acc[i][j][r] + bp[m0 + row + r];
    }
  }
}

extern "C" void kernel_launch(void* const* d_in, const int* in_sizes, int n_in,
                              void* d_out, int out_size, void* d_ws,
                              size_t ws_size, hipStream_t stream) {
  const float* x = (const float*)d_in[0];
  const float* wq = (const float*)d_in[1];
  const float* wk = (const float*)d_in[2];
  const float* wv = (const float*)d_in[3];
  const float* wh = (const float*)d_in[4];
  const float* gm = (const float*)d_in[5];
  const float* bt = (const float*)d_in[6];
  const float* wp = (const float*)d_in[7];
  const float* bp = (const float*)d_in[8];
  float* y = (float*)d_out;
  char* wsb = (char*)d_ws;

  u16* Qt = (u16*)(wsb + QT_OFF);
  u16* Kt = (u16*)(wsb + KT_OFF);
  u16* V = (u16*)(wsb + V_OFF);
  u16* Xt = (u16*)(wsb + XT_OFF);
  u16* Opart = (u16*)(wsb + OPART_OFF);
  float* lpart = (float*)(wsb + LP_OFF);
  float* l2part = (float*)(wsb + L2P_OFF);
  float* ab = (float*)(wsb + AB_OFF);
  float* vsum = (float*)(wsb + VSUM_OFF);
  u16* Og = (u16*)(wsb + O_OFF);

  transpose_x<<<dim3(16, 8, 4), 256, 0, stream>>>(x, Xt);
  gemm_qkt<<<dim3(8, 4, 8), 256, 0, stream>>>(Xt, wq, wk, Qt, Kt);
  gemm_v<<<dim3(8, 4, 4), 256, 0, stream>>>(Xt, wv, V);
  vsum_k<<<dim3(32), 256, 0, stream>>>(V, vsum);
  fused_attn<<<dim3(64, 2, 4), 256, 0, stream>>>(Qt, Kt, V, wh, Opart, lpart,
                                                 l2part);
  reduce_stats<<<dim3(32), 256, 0, stream>>>(lpart, l2part, gm, bt, ab);
  combine<<<dim3(256), 256, 0, stream>>>(Opart, lpart, ab, vsum, Og);
  gemm_proj<<<dim3(8, 4, 4), 256, 0, stream>>>(Og, wp, bp, y);
}